// Round 6
// baseline (3523.449 us; speedup 1.0000x reference)
//
#include <hip/hip_runtime.h>
#include <math.h>

#define TPQ 60
#define TPP 400
#define BB  16
#define II  256
#define HH  256

typedef short bf16x8 __attribute__((ext_vector_type(8)));
typedef float f32x4  __attribute__((ext_vector_type(4)));
typedef unsigned short u16;

__device__ __forceinline__ float sigm(float x){ return 1.0f/(1.0f+__expf(-x)); }
__device__ __forceinline__ float tanhfast(float x){
  x = fminf(fmaxf(x,-20.0f),20.0f);
  float t = __expf(2.0f*x);
  return (t-1.0f)/(t+1.0f);
}
__device__ __forceinline__ short f2bf(float f){
  unsigned u = __float_as_uint(f);
  unsigned r = (u + 0x7fffu + ((u>>16)&1u)) >> 16;
  return (short)r;
}
__device__ __forceinline__ float bf2f(short h){
  return __uint_as_float(((unsigned)(unsigned short)h)<<16);
}

// dst[c*dstStride + dstOff + r] = src[r*C + c]
__global__ void transpose_k(float* __restrict__ dst, const float* __restrict__ src,
                            int R, int C, int dstStride, int dstOff){
  int idx = blockIdx.x*256 + threadIdx.x;
  if (idx >= R*C) return;
  int r = idx / C, c = idx % C;
  dst[(size_t)c*dstStride + dstOff + r] = src[idx];
}

__global__ void f2bf_k(const float* __restrict__ src, u16* __restrict__ dst, int n){
  int i = blockIdx.x*256 + threadIdx.x;
  if (i < n) dst[i] = (u16)f2bf(src[i]);
}

// C[M][N] = A[M][K] @ B[K][N] (+bias) ; EP==1: C = msrc * sigmoid(C), also emits bf16 hi/lo
template<int EP>
__global__ __launch_bounds__(256) void gemm_f32(const float* __restrict__ A, const float* __restrict__ B,
    const float* __restrict__ bias, const float* __restrict__ msrc, float* __restrict__ C,
    u16* __restrict__ ohi, u16* __restrict__ olo,
    int M, int N, int K)
{
  __shared__ float As[8][128];
  __shared__ float Bs[8][128];
  int tid = threadIdx.x;
  int m0 = blockIdx.y*128, n0 = blockIdx.x*128;
  int tx = tid & 15, ty = tid >> 4;
  float acc[8][8];
  #pragma unroll
  for (int i=0;i<8;i++)
    #pragma unroll
    for (int j=0;j<8;j++) acc[i][j] = 0.0f;

  int arow = tid >> 1, ak = (tid & 1)*4;
  int brow = tid >> 5, bcol = (tid & 31)*4;

  for (int k0=0;k0<K;k0+=8){
    float4 av;
    if (m0 + arow < M) av = *reinterpret_cast<const float4*>(&A[(size_t)(m0+arow)*K + k0 + ak]);
    else { av.x=0; av.y=0; av.z=0; av.w=0; }
    As[ak+0][arow]=av.x; As[ak+1][arow]=av.y; As[ak+2][arow]=av.z; As[ak+3][arow]=av.w;
    float4 bv = *reinterpret_cast<const float4*>(&B[(size_t)(k0+brow)*N + n0 + bcol]);
    *reinterpret_cast<float4*>(&Bs[brow][bcol]) = bv;
    __syncthreads();
    #pragma unroll
    for (int k=0;k<8;k++){
      float a[8], bb[8];
      *reinterpret_cast<float4*>(&a[0]) = *reinterpret_cast<const float4*>(&As[k][ty*8]);
      *reinterpret_cast<float4*>(&a[4]) = *reinterpret_cast<const float4*>(&As[k][ty*8+4]);
      *reinterpret_cast<float4*>(&bb[0]) = *reinterpret_cast<const float4*>(&Bs[k][tx*8]);
      *reinterpret_cast<float4*>(&bb[4]) = *reinterpret_cast<const float4*>(&Bs[k][tx*8+4]);
      #pragma unroll
      for (int i=0;i<8;i++)
        #pragma unroll
        for (int j=0;j<8;j++) acc[i][j] += a[i]*bb[j];
    }
    __syncthreads();
  }
  #pragma unroll
  for (int i=0;i<8;i++){
    int m = m0 + ty*8 + i;
    if (m >= M) continue;
    #pragma unroll
    for (int j=0;j<8;j++){
      int n = n0 + tx*8 + j;
      float val = acc[i][j];
      if (bias) val += bias[n];
      if (EP==1){
        val = msrc[(size_t)m*N + n] * sigm(val);
        short hi = f2bf(val);
        ohi[(size_t)m*N + n] = (u16)hi;
        olo[(size_t)m*N + n] = (u16)f2bf(val - bf2f(hi));
      }
      C[(size_t)m*N + n] = val;
    }
  }
}

// ---------------------------------------------------------------------------
// bf16 MFMA GEMM with hi/lo-split A:  C[M][N] = (Ahi+Alo)[M][K] @ W[N][K]^T + bias
// tile 128x128, K-step 32, 256 threads (4 waves, 2x2 quadrants of 64x64).
// LDS in fragment order: index ((row>>4)*64 + kq*16 + (row&15)) * 8 elems
// -> both staging writes and fragment reads are conflict-free 1KB wave blocks.
// Requires M%128==0, N%128==0, K%32==0.
// ---------------------------------------------------------------------------
__global__ __launch_bounds__(256) void gemm_bf16_hl(
    const u16* __restrict__ Ahi, const u16* __restrict__ Alo,  // [M][K]
    const u16* __restrict__ Wb,                                 // [N][K]
    const float* __restrict__ bias,                             // [N]
    float* __restrict__ C, int M, int N, int K)
{
  __shared__ u16 sAh[4096], sAl[4096], sW[4096];
  const int tid = threadIdx.x;
  const int lane = tid & 63, wv = tid >> 6;
  const int nl = lane & 15, kq = lane >> 4;
  const int m0 = blockIdx.y*128, n0 = blockIdx.x*128;
  const int wm16 = (wv>>1)*4, wn16 = (wv&1)*4;   // tile indices /16

  f32x4 acc[4][4];
  #pragma unroll
  for (int mi=0;mi<4;mi++)
    #pragma unroll
    for (int ni=0;ni<4;ni++) acc[mi][ni] = (f32x4){0.f,0.f,0.f,0.f};

  for (int k0=0; k0<K; k0+=32){
    #pragma unroll
    for (int it=0; it<2; it++){
      int c = tid + it*256;
      int row = c >> 2, q = c & 3;
      int ldsoff = ((row>>4)*64 + q*16 + (row&15))*8;
      size_t ga = (size_t)(m0+row)*K + k0 + q*8;
      size_t gw = (size_t)(n0+row)*K + k0 + q*8;
      *reinterpret_cast<uint4*>(&sAh[ldsoff]) = *reinterpret_cast<const uint4*>(&Ahi[ga]);
      *reinterpret_cast<uint4*>(&sAl[ldsoff]) = *reinterpret_cast<const uint4*>(&Alo[ga]);
      *reinterpret_cast<uint4*>(&sW [ldsoff]) = *reinterpret_cast<const uint4*>(&Wb [gw]);
    }
    __syncthreads();
    bf16x8 ah[4], al[4], wr[4];
    #pragma unroll
    for (int mi=0;mi<4;mi++){
      int off = ((wm16+mi)*64 + kq*16 + nl)*8;
      ah[mi] = *reinterpret_cast<const bf16x8*>(&sAh[off]);
      al[mi] = *reinterpret_cast<const bf16x8*>(&sAl[off]);
    }
    #pragma unroll
    for (int ni=0;ni<4;ni++){
      int off = ((wn16+ni)*64 + kq*16 + nl)*8;
      wr[ni] = *reinterpret_cast<const bf16x8*>(&sW[off]);
    }
    #pragma unroll
    for (int mi=0;mi<4;mi++)
      #pragma unroll
      for (int ni=0;ni<4;ni++){
        acc[mi][ni] = __builtin_amdgcn_mfma_f32_16x16x32_bf16(ah[mi], wr[ni], acc[mi][ni], 0, 0, 0);
        acc[mi][ni] = __builtin_amdgcn_mfma_f32_16x16x32_bf16(al[mi], wr[ni], acc[mi][ni], 0, 0, 0);
      }
    __syncthreads();
  }
  // epilogue: D col = nl, row = kq*4 + r within tile
  #pragma unroll
  for (int mi=0;mi<4;mi++){
    #pragma unroll
    for (int ni=0;ni<4;ni++){
      int col = n0 + (wn16+ni)*16 + nl;
      float bv = bias ? bias[col] : 0.0f;
      #pragma unroll
      for (int r2=0;r2<4;r2++){
        int rrow = m0 + (wm16+mi)*16 + kq*4 + r2;
        C[(size_t)rrow*N + col] = acc[mi][ni][r2] + bv;
      }
    }
  }
}

// one block per (p,b): scores over q (tanh attention), softmax over q, ct, concat write
__global__ __launch_bounds__(256) void attn_k(const float* __restrict__ Qh, const float* __restrict__ Ph,
   const float* __restrict__ qrep, const float* __restrict__ prep, const float* __restrict__ v,
   const float* __restrict__ qmask, float* __restrict__ xcat)
{
  int p = blockIdx.x, b = blockIdx.y;
  int tid = threadIdx.x;
  __shared__ float ph[HH];
  __shared__ float vv[HH];
  __shared__ float sc[64];
  size_t pb = (size_t)p*BB + b;
  ph[tid] = Ph[pb*HH + tid];
  vv[tid] = v[tid];
  xcat[pb*512 + tid] = prep[pb*II + tid];
  __syncthreads();
  int wid = tid >> 6, lane = tid & 63;
  for (int q = wid; q < TPQ; q += 4){
    const float* qh = Qh + ((size_t)q*BB + b)*HH;
    float s = 0.0f;
    for (int hh = lane; hh < HH; hh += 64)
      s += vv[hh]*tanhfast(qh[hh] + ph[hh]);
    #pragma unroll
    for (int off=32; off>0; off>>=1) s += __shfl_xor(s, off);
    if (lane==0) sc[q] = s;
  }
  __syncthreads();
  if (wid==0){
    float m = (lane < TPQ) ? qmask[lane*BB + b] : 0.0f;
    float val = (lane < TPQ) ? (m*sc[lane] + (1.0f-m)*(-1e30f)) : -INFINITY;
    float mx = val;
    #pragma unroll
    for (int off=32; off>0; off>>=1) mx = fmaxf(mx, __shfl_xor(mx, off));
    float e = (lane < TPQ) ? __expf(val - mx) : 0.0f;
    float sum = e;
    #pragma unroll
    for (int off=32; off>0; off>>=1) sum += __shfl_xor(sum, off);
    if (lane < TPQ) sc[lane] = e / sum;
  }
  __syncthreads();
  float acc = 0.0f;
  for (int q=0;q<TPQ;q++)
    acc += sc[q] * qrep[((size_t)q*BB + b)*II + tid];
  xcat[pb*512 + 256 + tid] = acc;
}

// ---------------------------------------------------------------------------
// Persistent MFMA GRU scan v4: chain-parallel. grid = 32 (b,dir), block = 512.
// Full Whh (bf16) in regs (48 frags/lane). h: 256-bf16 ping-pong LDS broadcast.
// acc initialized with bhh; xv prefetched one step ahead; pointer-increment
// addressing. Emits bf16 hi/lo of output when xhi != null (feeds next layer).
// ---------------------------------------------------------------------------
__global__ __launch_bounds__(512) void gru_scan_mfma(
    const float* __restrict__ xg,    // [TPP][16][1536]
    const float* __restrict__ Whh,   // [2][768][256]
    const float* __restrict__ bhh,   // [2][768]
    float* __restrict__ out,         // [TPP][16][512]
    u16* __restrict__ xhi, u16* __restrict__ xlo)
{
  __shared__ u16 hbuf[2][256];

  const int b   = blockIdx.x & 15;
  const int dir = blockIdx.x >> 4;
  const int tid  = threadIdx.x;
  const int wv   = tid >> 6;
  const int lane = tid & 63;
  const int nl   = lane & 15;
  const int kq   = lane >> 4;

  ((u16*)hbuf)[tid] = 0;

  // Whh fragments bf16, all in registers. 16x16x32 B layout: n=lane&15, k=ks*32+kq*8+e
  bf16x8 wreg[8][6];
  #pragma unroll
  for (int ks=0; ks<8; ks++){
    #pragma unroll
    for (int gg=0; gg<2; gg++){
      #pragma unroll
      for (int gi=0; gi<3; gi++){
        int nrow = gi*256 + wv*32 + gg*16 + nl;
        const float* wsrc = Whh + (size_t)dir*768*256 + (size_t)nrow*256 + ks*32 + kq*8;
        float4 lo = *reinterpret_cast<const float4*>(wsrc);
        float4 hi = *reinterpret_cast<const float4*>(wsrc+4);
        bf16x8 f;
        f[0]=f2bf(lo.x); f[1]=f2bf(lo.y); f[2]=f2bf(lo.z); f[3]=f2bf(lo.w);
        f[4]=f2bf(hi.x); f[5]=f2bf(hi.y); f[6]=f2bf(hi.z); f[7]=f2bf(hi.w);
        wreg[ks][gg*3+gi] = f;
      }
    }
  }

  float bias[2][3];
  #pragma unroll
  for (int gg=0; gg<2; gg++)
    #pragma unroll
    for (int gi=0; gi<3; gi++)
      bias[gg][gi] = bhh[dir*768 + gi*256 + wv*32 + gg*16 + nl];

  const int t0  = dir ? (TPP-1) : 0;
  const ptrdiff_t xstride = (dir ? -1 : 1) * (ptrdiff_t)(16*1536);
  const ptrdiff_t ostride = (dir ? -1 : 1) * (ptrdiff_t)(16*512);
  const float* xp = xg + (size_t)(t0*16 + b)*1536 + dir*768 + wv*32 + nl;
  float* op = out + (size_t)(t0*16 + b)*512 + dir*256 + wv*32 + nl;
  size_t xoff = (size_t)(t0*16 + b)*512 + dir*256 + wv*32 + nl;

  float hold[2] = {0.0f, 0.0f};

  __syncthreads();

  // preload xv for s=0
  float xv[2][3];
  #pragma unroll
  for (int gg=0; gg<2; gg++)
    #pragma unroll
    for (int gi=0; gi<3; gi++)
      xv[gg][gi] = xp[gi*256 + gg*16];

  #pragma unroll 1
  for (int s=0; s<TPP; s++){
    // prefetch next step's xv (full step of slack)
    float xn[2][3];
    if (s+1 < TPP){
      const float* xq = xp + xstride;
      #pragma unroll
      for (int gg=0; gg<2; gg++)
        #pragma unroll
        for (int gi=0; gi<3; gi++)
          xn[gg][gi] = xq[gi*256 + gg*16];
    }

    f32x4 acc[2][3];
    #pragma unroll
    for (int gg=0; gg<2; gg++)
      #pragma unroll
      for (int gi=0; gi<3; gi++){
        float bv = bias[gg][gi];
        acc[gg][gi] = (f32x4){bv,bv,bv,bv};
      }

    const char* hp = (const char*)hbuf[s&1];
    bf16x8 a = *reinterpret_cast<const bf16x8*>(hp + kq*16);
    #pragma unroll
    for (int ks=0; ks<8; ks++){
      bf16x8 an;
      if (ks < 7)
        an = *reinterpret_cast<const bf16x8*>(hp + (ks+1)*64 + kq*16);
      #pragma unroll
      for (int gg=0; gg<2; gg++)
        #pragma unroll
        for (int gi=0; gi<3; gi++)
          acc[gg][gi] = __builtin_amdgcn_mfma_f32_16x16x32_bf16(a, wreg[ks][gg*3+gi], acc[gg][gi], 0, 0, 0);
      if (ks < 7) a = an;
    }

    if (lane < 16){
      u16* wb = hbuf[(s&1)^1];
      #pragma unroll
      for (int gg=0; gg<2; gg++){
        int j = wv*32 + gg*16 + nl;
        float r = sigm(xv[gg][0] + acc[gg][0][0]);
        float z = sigm(xv[gg][1] + acc[gg][1][0]);
        float n = tanhfast(xv[gg][2] + r*acc[gg][2][0]);
        float hv = (1.0f - z)*n + z*hold[gg];
        hold[gg] = hv;
        short hb = f2bf(hv);
        wb[j] = (u16)hb;
        op[gg*16] = hv;
        if (xhi){
          xhi[xoff + gg*16] = (u16)hb;
          xlo[xoff + gg*16] = (u16)f2bf(hv - bf2f(hb));
        }
      }
    }
    #pragma unroll
    for (int gg=0; gg<2; gg++)
      #pragma unroll
      for (int gi=0; gi<3; gi++)
        xv[gg][gi] = xn[gg][gi];
    xp += xstride; op += ostride; xoff += ostride;
    __syncthreads();
  }
}

extern "C" void kernel_launch(void* const* d_in, const int* in_sizes, int n_in,
                              void* d_out, int out_size, void* d_ws, size_t ws_size,
                              hipStream_t stream)
{
  const float* prep  = (const float*)d_in[0];
  const float* qrep  = (const float*)d_in[1];
  const float* qmask = (const float*)d_in[3];
  const float* WuQ   = (const float*)d_in[4];
  const float* WuP   = (const float*)d_in[5];
  const float* v     = (const float*)d_in[6];
  const float* Wg    = (const float*)d_in[7];
  const float* Wih   = (const float*)d_in[8];
  const float* Whh   = (const float*)d_in[9];
  const float* bih   = (const float*)d_in[10];
  const float* bhh   = (const float*)d_in[11];
  float* out = (float*)d_out;

  float* ws = (float*)d_ws;
  size_t off = 0;
  float* WuQT = ws + off; off += 256*256;
  float* WuPT = ws + off; off += 256*256;
  float* WgT  = ws + off; off += 512*512;
  float* Qh   = ws + off; off += (size_t)TPQ*BB*HH;
  float* Ph   = ws + off; off += (size_t)TPP*BB*HH;
  float* xcat = ws + off; off += (size_t)TPP*BB*512;
  float* ybuf = ws + off; off += (size_t)TPP*BB*512;
  float* xg   = ws + off; off += (size_t)TPP*BB*1536;
  u16*  Wb    = (u16*)(ws + off); off += (size_t)3*1536*512/2;
  u16*  xbh   = (u16*)(ws + off); off += (size_t)TPP*BB*512/2;
  u16*  xbl   = (u16*)(ws + off); off += (size_t)TPP*BB*512/2;

  auto T = [&](float* dst, const float* src, int R, int C, int st, int o){
    int n = R*C;
    transpose_k<<<dim3((n+255)/256), dim3(256), 0, stream>>>(dst, src, R, C, st, o);
  };
  T(WuQT, WuQ, 256,256,256,0);
  T(WuPT, WuP, 256,256,256,0);
  T(WgT,  Wg,  512,512,512,0);
  {
    int n = 3*1536*512;
    f2bf_k<<<dim3((n+255)/256), dim3(256), 0, stream>>>(Wih, Wb, n);
  }

  // Qh = question @ WuQ.T : M=960, N=256, K=256
  gemm_f32<0><<<dim3(2, 8), dim3(256), 0, stream>>>(qrep, WuQT, nullptr, nullptr, Qh, nullptr, nullptr, TPQ*BB, 256, 256);
  // Ph = passage @ WuP.T : M=6400
  gemm_f32<0><<<dim3(2, 50), dim3(256), 0, stream>>>(prep, WuPT, nullptr, nullptr, Ph, nullptr, nullptr, TPP*BB, 256, 256);
  // attention + concat
  attn_k<<<dim3(TPP, BB), dim3(256), 0, stream>>>(Qh, Ph, qrep, prep, v, qmask, xcat);
  // gate: ybuf = xcat * sigmoid(xcat @ Wg.T), plus bf16 hi/lo copy
  gemm_f32<1><<<dim3(4, 50), dim3(256), 0, stream>>>(xcat, WgT, nullptr, xcat, ybuf, xbh, xbl, TPP*BB, 512, 512);

  for (int l=0;l<3;l++){
    // xg = x @ Wih[l].T + bih[l]  via bf16 MFMA (A = hi/lo split)
    gemm_bf16_hl<<<dim3(12, 50), dim3(256), 0, stream>>>(xbh, xbl, Wb + (size_t)l*1536*512,
                                                         bih + (size_t)l*1536, xg, TPP*BB, 1536, 512);
    float* o = (l==2) ? out : ((l&1) ? ybuf : xcat);
    gru_scan_mfma<<<dim3(32), dim3(512), 0, stream>>>(xg, Whh + (size_t)l*2*768*256,
                                                      bhh + (size_t)l*2*768, o,
                                                      (l<2) ? xbh : nullptr, (l<2) ? xbl : nullptr);
  }
}

// Round 7
// 3390.831 us; speedup vs baseline: 1.0391x; 1.0391x over previous
//
#include <hip/hip_runtime.h>
#include <math.h>

#define TPQ 60
#define TPP 400
#define BB  16
#define II  256
#define HH  256

typedef short bf16x8 __attribute__((ext_vector_type(8)));
typedef float f32x4  __attribute__((ext_vector_type(4)));
typedef unsigned short u16;

__device__ __forceinline__ float sigm(float x){ return 1.0f/(1.0f+__expf(-x)); }
__device__ __forceinline__ float tanhfast(float x){
  x = fminf(fmaxf(x,-20.0f),20.0f);
  float t = __expf(2.0f*x);
  return (t-1.0f)/(t+1.0f);
}
__device__ __forceinline__ short f2bf(float f){
  unsigned u = __float_as_uint(f);
  unsigned r = (u + 0x7fffu + ((u>>16)&1u)) >> 16;
  return (short)r;
}
__device__ __forceinline__ float bf2f(short h){
  return __uint_as_float(((unsigned)(unsigned short)h)<<16);
}

// dst[c*dstStride + dstOff + r] = src[r*C + c]
__global__ void transpose_k(float* __restrict__ dst, const float* __restrict__ src,
                            int R, int C, int dstStride, int dstOff){
  int idx = blockIdx.x*256 + threadIdx.x;
  if (idx >= R*C) return;
  int r = idx / C, c = idx % C;
  dst[(size_t)c*dstStride + dstOff + r] = src[idx];
}

__global__ void f2bf_k(const float* __restrict__ src, u16* __restrict__ dst, int n){
  int i = blockIdx.x*256 + threadIdx.x;
  if (i < n) dst[i] = (u16)f2bf(src[i]);
}

// C[M][N] = A[M][K] @ B[K][N] (+bias) ; EP==1: C = msrc * sigmoid(C)
template<int EP>
__global__ __launch_bounds__(256) void gemm_f32(const float* __restrict__ A, const float* __restrict__ B,
    const float* __restrict__ bias, const float* __restrict__ msrc, float* __restrict__ C,
    int M, int N, int K)
{
  __shared__ float As[8][128];
  __shared__ float Bs[8][128];
  int tid = threadIdx.x;
  int m0 = blockIdx.y*128, n0 = blockIdx.x*128;
  int tx = tid & 15, ty = tid >> 4;
  float acc[8][8];
  #pragma unroll
  for (int i=0;i<8;i++)
    #pragma unroll
    for (int j=0;j<8;j++) acc[i][j] = 0.0f;

  int arow = tid >> 1, ak = (tid & 1)*4;
  int brow = tid >> 5, bcol = (tid & 31)*4;

  for (int k0=0;k0<K;k0+=8){
    float4 av;
    if (m0 + arow < M) av = *reinterpret_cast<const float4*>(&A[(size_t)(m0+arow)*K + k0 + ak]);
    else { av.x=0; av.y=0; av.z=0; av.w=0; }
    As[ak+0][arow]=av.x; As[ak+1][arow]=av.y; As[ak+2][arow]=av.z; As[ak+3][arow]=av.w;
    float4 bv = *reinterpret_cast<const float4*>(&B[(size_t)(k0+brow)*N + n0 + bcol]);
    *reinterpret_cast<float4*>(&Bs[brow][bcol]) = bv;
    __syncthreads();
    #pragma unroll
    for (int k=0;k<8;k++){
      float a[8], bb[8];
      *reinterpret_cast<float4*>(&a[0]) = *reinterpret_cast<const float4*>(&As[k][ty*8]);
      *reinterpret_cast<float4*>(&a[4]) = *reinterpret_cast<const float4*>(&As[k][ty*8+4]);
      *reinterpret_cast<float4*>(&bb[0]) = *reinterpret_cast<const float4*>(&Bs[k][tx*8]);
      *reinterpret_cast<float4*>(&bb[4]) = *reinterpret_cast<const float4*>(&Bs[k][tx*8+4]);
      #pragma unroll
      for (int i=0;i<8;i++)
        #pragma unroll
        for (int j=0;j<8;j++) acc[i][j] += a[i]*bb[j];
    }
    __syncthreads();
  }
  #pragma unroll
  for (int i=0;i<8;i++){
    int m = m0 + ty*8 + i;
    if (m >= M) continue;
    #pragma unroll
    for (int j=0;j<8;j++){
      int n = n0 + tx*8 + j;
      float val = acc[i][j];
      if (bias) val += bias[n];
      if (EP==1) val = msrc[(size_t)m*N + n] * sigm(val);
      C[(size_t)m*N + n] = val;
    }
  }
}

// ---------------------------------------------------------------------------
// bf16 MFMA GEMM, A supplied as f32 and hi/lo-split during LDS staging:
//   C[M][N] = A[M][K] @ W[N][K]^T + bias   (exact-ish: A split into 2 bf16)
// tile 128x128, K-step 32, 256 threads (4 waves, 2x2 quadrants of 64x64).
// LDS in fragment order -> staging writes and fragment reads conflict-free.
// Requires M%128==0, N%128==0, K%32==0.
// ---------------------------------------------------------------------------
__global__ __launch_bounds__(256) void gemm_bf16_hl(
    const float* __restrict__ Af,   // [M][K] f32
    const u16* __restrict__ Wb,     // [N][K] bf16
    const float* __restrict__ bias, // [N]
    float* __restrict__ C, int M, int N, int K)
{
  __shared__ u16 sAh[4096], sAl[4096], sW[4096];
  const int tid = threadIdx.x;
  const int lane = tid & 63, wv = tid >> 6;
  const int nl = lane & 15, kq = lane >> 4;
  const int m0 = blockIdx.y*128, n0 = blockIdx.x*128;
  const int wm16 = (wv>>1)*4, wn16 = (wv&1)*4;   // tile indices /16

  f32x4 acc[4][4];
  #pragma unroll
  for (int mi=0;mi<4;mi++)
    #pragma unroll
    for (int ni=0;ni<4;ni++) acc[mi][ni] = (f32x4){0.f,0.f,0.f,0.f};

  for (int k0=0; k0<K; k0+=32){
    #pragma unroll
    for (int it=0; it<2; it++){
      int c = tid + it*256;
      int row = c >> 2, q = c & 3;
      int ldsoff = ((row>>4)*64 + q*16 + (row&15))*8;
      size_t ga = (size_t)(m0+row)*K + k0 + q*8;
      float4 a0 = *reinterpret_cast<const float4*>(&Af[ga]);
      float4 a1 = *reinterpret_cast<const float4*>(&Af[ga+4]);
      bf16x8 h, l;
      float av[8] = {a0.x,a0.y,a0.z,a0.w,a1.x,a1.y,a1.z,a1.w};
      #pragma unroll
      for (int e=0;e<8;e++){
        short hb = f2bf(av[e]);
        h[e] = hb;
        l[e] = f2bf(av[e] - bf2f(hb));
      }
      *reinterpret_cast<bf16x8*>(&sAh[ldsoff]) = h;
      *reinterpret_cast<bf16x8*>(&sAl[ldsoff]) = l;
      size_t gw = (size_t)(n0+row)*K + k0 + q*8;
      *reinterpret_cast<uint4*>(&sW[ldsoff]) = *reinterpret_cast<const uint4*>(&Wb[gw]);
    }
    __syncthreads();
    bf16x8 ah[4], al[4], wr[4];
    #pragma unroll
    for (int mi=0;mi<4;mi++){
      int off = ((wm16+mi)*64 + kq*16 + nl)*8;
      ah[mi] = *reinterpret_cast<const bf16x8*>(&sAh[off]);
      al[mi] = *reinterpret_cast<const bf16x8*>(&sAl[off]);
    }
    #pragma unroll
    for (int ni=0;ni<4;ni++){
      int off = ((wn16+ni)*64 + kq*16 + nl)*8;
      wr[ni] = *reinterpret_cast<const bf16x8*>(&sW[off]);
    }
    #pragma unroll
    for (int mi=0;mi<4;mi++)
      #pragma unroll
      for (int ni=0;ni<4;ni++){
        acc[mi][ni] = __builtin_amdgcn_mfma_f32_16x16x32_bf16(ah[mi], wr[ni], acc[mi][ni], 0, 0, 0);
        acc[mi][ni] = __builtin_amdgcn_mfma_f32_16x16x32_bf16(al[mi], wr[ni], acc[mi][ni], 0, 0, 0);
      }
    __syncthreads();
  }
  // epilogue: D col = nl, row = kq*4 + r within tile
  #pragma unroll
  for (int mi=0;mi<4;mi++){
    #pragma unroll
    for (int ni=0;ni<4;ni++){
      int col = n0 + (wn16+ni)*16 + nl;
      float bv = bias ? bias[col] : 0.0f;
      #pragma unroll
      for (int r2=0;r2<4;r2++){
        int rrow = m0 + (wm16+mi)*16 + kq*4 + r2;
        C[(size_t)rrow*N + col] = acc[mi][ni][r2] + bv;
      }
    }
  }
}

// one block per (p,b): scores over q (tanh attention), softmax over q, ct, concat write
__global__ __launch_bounds__(256) void attn_k(const float* __restrict__ Qh, const float* __restrict__ Ph,
   const float* __restrict__ qrep, const float* __restrict__ prep, const float* __restrict__ v,
   const float* __restrict__ qmask, float* __restrict__ xcat)
{
  int p = blockIdx.x, b = blockIdx.y;
  int tid = threadIdx.x;
  __shared__ float ph[HH];
  __shared__ float vv[HH];
  __shared__ float sc[64];
  size_t pb = (size_t)p*BB + b;
  ph[tid] = Ph[pb*HH + tid];
  vv[tid] = v[tid];
  xcat[pb*512 + tid] = prep[pb*II + tid];
  __syncthreads();
  int wid = tid >> 6, lane = tid & 63;
  for (int q = wid; q < TPQ; q += 4){
    const float* qh = Qh + ((size_t)q*BB + b)*HH;
    float s = 0.0f;
    for (int hh = lane; hh < HH; hh += 64)
      s += vv[hh]*tanhfast(qh[hh] + ph[hh]);
    #pragma unroll
    for (int off=32; off>0; off>>=1) s += __shfl_xor(s, off);
    if (lane==0) sc[q] = s;
  }
  __syncthreads();
  if (wid==0){
    float m = (lane < TPQ) ? qmask[lane*BB + b] : 0.0f;
    float val = (lane < TPQ) ? (m*sc[lane] + (1.0f-m)*(-1e30f)) : -INFINITY;
    float mx = val;
    #pragma unroll
    for (int off=32; off>0; off>>=1) mx = fmaxf(mx, __shfl_xor(mx, off));
    float e = (lane < TPQ) ? __expf(val - mx) : 0.0f;
    float sum = e;
    #pragma unroll
    for (int off=32; off>0; off>>=1) sum += __shfl_xor(sum, off);
    if (lane < TPQ) sc[lane] = e / sum;
  }
  __syncthreads();
  float acc = 0.0f;
  for (int q=0;q<TPQ;q++)
    acc += sc[q] * qrep[((size_t)q*BB + b)*II + tid];
  xcat[pb*512 + 256 + tid] = acc;
}

// ---------------------------------------------------------------------------
// Persistent MFMA GRU scan v5: chain-parallel. grid = 32 (b,dir), block = 512.
// Full Whh (bf16) in regs (48 frags/lane). h: 256-bf16 ping-pong LDS broadcast.
// acc initialized with bhh; xv prefetched one step ahead; pointer-increment
// addressing. NO extra global writes on the serial path (R6 lesson).
// ---------------------------------------------------------------------------
__global__ __launch_bounds__(512) void gru_scan_mfma(
    const float* __restrict__ xg,    // [TPP][16][1536]
    const float* __restrict__ Whh,   // [2][768][256]
    const float* __restrict__ bhh,   // [2][768]
    float* __restrict__ out)         // [TPP][16][512]
{
  __shared__ u16 hbuf[2][256];

  const int b   = blockIdx.x & 15;
  const int dir = blockIdx.x >> 4;
  const int tid  = threadIdx.x;
  const int wv   = tid >> 6;
  const int lane = tid & 63;
  const int nl   = lane & 15;
  const int kq   = lane >> 4;

  ((u16*)hbuf)[tid] = 0;

  // Whh fragments bf16, all in registers. 16x16x32 B layout: n=lane&15, k=ks*32+kq*8+e
  bf16x8 wreg[8][6];
  #pragma unroll
  for (int ks=0; ks<8; ks++){
    #pragma unroll
    for (int gg=0; gg<2; gg++){
      #pragma unroll
      for (int gi=0; gi<3; gi++){
        int nrow = gi*256 + wv*32 + gg*16 + nl;
        const float* wsrc = Whh + (size_t)dir*768*256 + (size_t)nrow*256 + ks*32 + kq*8;
        float4 lo = *reinterpret_cast<const float4*>(wsrc);
        float4 hi = *reinterpret_cast<const float4*>(wsrc+4);
        bf16x8 f;
        f[0]=f2bf(lo.x); f[1]=f2bf(lo.y); f[2]=f2bf(lo.z); f[3]=f2bf(lo.w);
        f[4]=f2bf(hi.x); f[5]=f2bf(hi.y); f[6]=f2bf(hi.z); f[7]=f2bf(hi.w);
        wreg[ks][gg*3+gi] = f;
      }
    }
  }

  float bias[2][3];
  #pragma unroll
  for (int gg=0; gg<2; gg++)
    #pragma unroll
    for (int gi=0; gi<3; gi++)
      bias[gg][gi] = bhh[dir*768 + gi*256 + wv*32 + gg*16 + nl];

  const int t0  = dir ? (TPP-1) : 0;
  const ptrdiff_t xstride = (dir ? -1 : 1) * (ptrdiff_t)(16*1536);
  const ptrdiff_t ostride = (dir ? -1 : 1) * (ptrdiff_t)(16*512);
  const float* xp = xg + (size_t)(t0*16 + b)*1536 + dir*768 + wv*32 + nl;
  float* op = out + (size_t)(t0*16 + b)*512 + dir*256 + wv*32 + nl;

  float hold[2] = {0.0f, 0.0f};

  __syncthreads();

  // preload xv for s=0
  float xv[2][3];
  #pragma unroll
  for (int gg=0; gg<2; gg++)
    #pragma unroll
    for (int gi=0; gi<3; gi++)
      xv[gg][gi] = xp[gi*256 + gg*16];

  #pragma unroll 1
  for (int s=0; s<TPP; s++){
    // prefetch next step's xv (full step of slack)
    float xn[2][3];
    if (s+1 < TPP){
      const float* xq = xp + xstride;
      #pragma unroll
      for (int gg=0; gg<2; gg++)
        #pragma unroll
        for (int gi=0; gi<3; gi++)
          xn[gg][gi] = xq[gi*256 + gg*16];
    }

    f32x4 acc[2][3];
    #pragma unroll
    for (int gg=0; gg<2; gg++)
      #pragma unroll
      for (int gi=0; gi<3; gi++){
        float bv = bias[gg][gi];
        acc[gg][gi] = (f32x4){bv,bv,bv,bv};
      }

    const char* hp = (const char*)hbuf[s&1];
    bf16x8 a = *reinterpret_cast<const bf16x8*>(hp + kq*16);
    #pragma unroll
    for (int ks=0; ks<8; ks++){
      bf16x8 an;
      if (ks < 7)
        an = *reinterpret_cast<const bf16x8*>(hp + (ks+1)*64 + kq*16);
      #pragma unroll
      for (int gg=0; gg<2; gg++)
        #pragma unroll
        for (int gi=0; gi<3; gi++)
          acc[gg][gi] = __builtin_amdgcn_mfma_f32_16x16x32_bf16(a, wreg[ks][gg*3+gi], acc[gg][gi], 0, 0, 0);
      if (ks < 7) a = an;
    }

    if (lane < 16){
      u16* wb = hbuf[(s&1)^1];
      #pragma unroll
      for (int gg=0; gg<2; gg++){
        int j = wv*32 + gg*16 + nl;
        float r = sigm(xv[gg][0] + acc[gg][0][0]);
        float z = sigm(xv[gg][1] + acc[gg][1][0]);
        float n = tanhfast(xv[gg][2] + r*acc[gg][2][0]);
        float hv = (1.0f - z)*n + z*hold[gg];
        hold[gg] = hv;
        wb[j] = (u16)f2bf(hv);
        op[gg*16] = hv;
      }
    }
    #pragma unroll
    for (int gg=0; gg<2; gg++)
      #pragma unroll
      for (int gi=0; gi<3; gi++)
        xv[gg][gi] = xn[gg][gi];
    xp += xstride; op += ostride;
    __syncthreads();
  }
}

extern "C" void kernel_launch(void* const* d_in, const int* in_sizes, int n_in,
                              void* d_out, int out_size, void* d_ws, size_t ws_size,
                              hipStream_t stream)
{
  const float* prep  = (const float*)d_in[0];
  const float* qrep  = (const float*)d_in[1];
  const float* qmask = (const float*)d_in[3];
  const float* WuQ   = (const float*)d_in[4];
  const float* WuP   = (const float*)d_in[5];
  const float* v     = (const float*)d_in[6];
  const float* Wg    = (const float*)d_in[7];
  const float* Wih   = (const float*)d_in[8];
  const float* Whh   = (const float*)d_in[9];
  const float* bih   = (const float*)d_in[10];
  const float* bhh   = (const float*)d_in[11];
  float* out = (float*)d_out;

  float* ws = (float*)d_ws;
  size_t off = 0;
  float* WuQT = ws + off; off += 256*256;
  float* WuPT = ws + off; off += 256*256;
  float* WgT  = ws + off; off += 512*512;
  float* Qh   = ws + off; off += (size_t)TPQ*BB*HH;
  float* Ph   = ws + off; off += (size_t)TPP*BB*HH;
  float* xcat = ws + off; off += (size_t)TPP*BB*512;
  float* ybuf = ws + off; off += (size_t)TPP*BB*512;
  float* xg   = ws + off; off += (size_t)TPP*BB*1536;
  u16*  Wb    = (u16*)(ws + off); off += (size_t)3*1536*512/2;

  auto T = [&](float* dst, const float* src, int R, int C, int st, int o){
    int n = R*C;
    transpose_k<<<dim3((n+255)/256), dim3(256), 0, stream>>>(dst, src, R, C, st, o);
  };
  T(WuQT, WuQ, 256,256,256,0);
  T(WuPT, WuP, 256,256,256,0);
  T(WgT,  Wg,  512,512,512,0);
  {
    int n = 3*1536*512;
    f2bf_k<<<dim3((n+255)/256), dim3(256), 0, stream>>>(Wih, Wb, n);
  }

  // Qh = question @ WuQ.T : M=960, N=256, K=256
  gemm_f32<0><<<dim3(2, 8), dim3(256), 0, stream>>>(qrep, WuQT, nullptr, nullptr, Qh, TPQ*BB, 256, 256);
  // Ph = passage @ WuP.T : M=6400
  gemm_f32<0><<<dim3(2, 50), dim3(256), 0, stream>>>(prep, WuPT, nullptr, nullptr, Ph, TPP*BB, 256, 256);
  // attention + concat
  attn_k<<<dim3(TPP, BB), dim3(256), 0, stream>>>(Qh, Ph, qrep, prep, v, qmask, xcat);
  // gate: ybuf = xcat * sigmoid(xcat @ Wg.T)
  gemm_f32<1><<<dim3(4, 50), dim3(256), 0, stream>>>(xcat, WgT, nullptr, xcat, ybuf, TPP*BB, 512, 512);

  float* cur = ybuf;
  float* nxt = xcat;
  for (int l=0;l<3;l++){
    // xg = cur @ Wih[l].T + bih[l]  via bf16 MFMA (A hi/lo split in staging)
    gemm_bf16_hl<<<dim3(12, 50), dim3(256), 0, stream>>>(cur, Wb + (size_t)l*1536*512,
                                                         bih + (size_t)l*1536, xg, TPP*BB, 1536, 512);
    float* o = (l==2) ? out : nxt;
    gru_scan_mfma<<<dim3(32), dim3(512), 0, stream>>>(xg, Whh + (size_t)l*2*768*256,
                                                      bhh + (size_t)l*2*768, o);
    float* tmp = cur; cur = o; nxt = tmp;
  }
}

// Round 8
// 2309.910 us; speedup vs baseline: 1.5254x; 1.4679x over previous
//
#include <hip/hip_runtime.h>
#include <math.h>

#define TPQ 60
#define TPP 400
#define BB  16
#define II  256
#define HH  256

typedef short bf16x8 __attribute__((ext_vector_type(8)));
typedef float f32x4  __attribute__((ext_vector_type(4)));
typedef unsigned short u16;

__device__ __forceinline__ float sigm(float x){ return 1.0f/(1.0f+__expf(-x)); }
__device__ __forceinline__ float tanhfast(float x){
  x = fminf(fmaxf(x,-20.0f),20.0f);
  float t = __expf(2.0f*x);
  return (t-1.0f)/(t+1.0f);
}
__device__ __forceinline__ short f2bf(float f){
  unsigned u = __float_as_uint(f);
  unsigned r = (u + 0x7fffu + ((u>>16)&1u)) >> 16;
  return (short)r;
}
__device__ __forceinline__ float bf2f(short h){
  return __uint_as_float(((unsigned)(unsigned short)h)<<16);
}

// dst[c*dstStride + dstOff + r] = src[r*C + c]
__global__ void transpose_k(float* __restrict__ dst, const float* __restrict__ src,
                            int R, int C, int dstStride, int dstOff){
  int idx = blockIdx.x*256 + threadIdx.x;
  if (idx >= R*C) return;
  int r = idx / C, c = idx % C;
  dst[(size_t)c*dstStride + dstOff + r] = src[idx];
}

__global__ void f2bf_k(const float* __restrict__ src, u16* __restrict__ dst, int n){
  int i = blockIdx.x*256 + threadIdx.x;
  if (i < n) dst[i] = (u16)f2bf(src[i]);
}

// C[M][N] = A[M][K] @ B[K][N] (+bias)
template<int EP>
__global__ __launch_bounds__(256) void gemm_f32(const float* __restrict__ A, const float* __restrict__ B,
    const float* __restrict__ bias, const float* __restrict__ msrc, float* __restrict__ C,
    int M, int N, int K)
{
  __shared__ float As[8][128];
  __shared__ float Bs[8][128];
  int tid = threadIdx.x;
  int m0 = blockIdx.y*128, n0 = blockIdx.x*128;
  int tx = tid & 15, ty = tid >> 4;
  float acc[8][8];
  #pragma unroll
  for (int i=0;i<8;i++)
    #pragma unroll
    for (int j=0;j<8;j++) acc[i][j] = 0.0f;

  int arow = tid >> 1, ak = (tid & 1)*4;
  int brow = tid >> 5, bcol = (tid & 31)*4;

  for (int k0=0;k0<K;k0+=8){
    float4 av;
    if (m0 + arow < M) av = *reinterpret_cast<const float4*>(&A[(size_t)(m0+arow)*K + k0 + ak]);
    else { av.x=0; av.y=0; av.z=0; av.w=0; }
    As[ak+0][arow]=av.x; As[ak+1][arow]=av.y; As[ak+2][arow]=av.z; As[ak+3][arow]=av.w;
    float4 bv = *reinterpret_cast<const float4*>(&B[(size_t)(k0+brow)*N + n0 + bcol]);
    *reinterpret_cast<float4*>(&Bs[brow][bcol]) = bv;
    __syncthreads();
    #pragma unroll
    for (int k=0;k<8;k++){
      float a[8], bb[8];
      *reinterpret_cast<float4*>(&a[0]) = *reinterpret_cast<const float4*>(&As[k][ty*8]);
      *reinterpret_cast<float4*>(&a[4]) = *reinterpret_cast<const float4*>(&As[k][ty*8+4]);
      *reinterpret_cast<float4*>(&bb[0]) = *reinterpret_cast<const float4*>(&Bs[k][tx*8]);
      *reinterpret_cast<float4*>(&bb[4]) = *reinterpret_cast<const float4*>(&Bs[k][tx*8+4]);
      #pragma unroll
      for (int i=0;i<8;i++)
        #pragma unroll
        for (int j=0;j<8;j++) acc[i][j] += a[i]*bb[j];
    }
    __syncthreads();
  }
  #pragma unroll
  for (int i=0;i<8;i++){
    int m = m0 + ty*8 + i;
    if (m >= M) continue;
    #pragma unroll
    for (int j=0;j<8;j++){
      int n = n0 + tx*8 + j;
      float val = acc[i][j];
      if (bias) val += bias[n];
      if (EP==1) val = msrc[(size_t)m*N + n] * sigm(val);
      C[(size_t)m*N + n] = val;
    }
  }
}

// ---------------------------------------------------------------------------
// bf16 MFMA GEMM, A supplied as f32 and hi/lo-split during LDS staging:
//   C[M][N] = A[M][K] @ W[N][K]^T (+bias)   EP==1: C = msrc * sigmoid(C)
// tile 128x128, K-step 32, 256 threads (4 waves, 2x2 quadrants of 64x64).
// LDS in fragment order -> staging writes and fragment reads conflict-free.
// Requires N%128==0, K%32==0; M guarded.
// ---------------------------------------------------------------------------
template<int EP>
__global__ __launch_bounds__(256) void gemm_bf16_hl(
    const float* __restrict__ Af,   // [M][K] f32
    const u16* __restrict__ Wb,     // [N][K] bf16
    const float* __restrict__ bias, // [N]
    const float* __restrict__ msrc, // [M][N] (EP==1)
    float* __restrict__ C, int M, int N, int K)
{
  __shared__ u16 sAh[4096], sAl[4096], sW[4096];
  const int tid = threadIdx.x;
  const int lane = tid & 63, wv = tid >> 6;
  const int nl = lane & 15, kq = lane >> 4;
  const int m0 = blockIdx.y*128, n0 = blockIdx.x*128;
  const int wm16 = (wv>>1)*4, wn16 = (wv&1)*4;   // tile indices /16

  f32x4 acc[4][4];
  #pragma unroll
  for (int mi=0;mi<4;mi++)
    #pragma unroll
    for (int ni=0;ni<4;ni++) acc[mi][ni] = (f32x4){0.f,0.f,0.f,0.f};

  for (int k0=0; k0<K; k0+=32){
    #pragma unroll
    for (int it=0; it<2; it++){
      int c = tid + it*256;
      int row = c >> 2, q = c & 3;
      int ldsoff = ((row>>4)*64 + q*16 + (row&15))*8;
      bf16x8 h = (bf16x8){0,0,0,0,0,0,0,0}, l = (bf16x8){0,0,0,0,0,0,0,0};
      if (m0 + row < M){
        size_t ga = (size_t)(m0+row)*K + k0 + q*8;
        float4 a0 = *reinterpret_cast<const float4*>(&Af[ga]);
        float4 a1 = *reinterpret_cast<const float4*>(&Af[ga+4]);
        float av[8] = {a0.x,a0.y,a0.z,a0.w,a1.x,a1.y,a1.z,a1.w};
        #pragma unroll
        for (int e=0;e<8;e++){
          short hb = f2bf(av[e]);
          h[e] = hb;
          l[e] = f2bf(av[e] - bf2f(hb));
        }
      }
      *reinterpret_cast<bf16x8*>(&sAh[ldsoff]) = h;
      *reinterpret_cast<bf16x8*>(&sAl[ldsoff]) = l;
      size_t gw = (size_t)(n0+row)*K + k0 + q*8;
      *reinterpret_cast<uint4*>(&sW[ldsoff]) = *reinterpret_cast<const uint4*>(&Wb[gw]);
    }
    __syncthreads();
    bf16x8 ah[4], al[4], wr[4];
    #pragma unroll
    for (int mi=0;mi<4;mi++){
      int off = ((wm16+mi)*64 + kq*16 + nl)*8;
      ah[mi] = *reinterpret_cast<const bf16x8*>(&sAh[off]);
      al[mi] = *reinterpret_cast<const bf16x8*>(&sAl[off]);
    }
    #pragma unroll
    for (int ni=0;ni<4;ni++){
      int off = ((wn16+ni)*64 + kq*16 + nl)*8;
      wr[ni] = *reinterpret_cast<const bf16x8*>(&sW[off]);
    }
    #pragma unroll
    for (int mi=0;mi<4;mi++)
      #pragma unroll
      for (int ni=0;ni<4;ni++){
        acc[mi][ni] = __builtin_amdgcn_mfma_f32_16x16x32_bf16(ah[mi], wr[ni], acc[mi][ni], 0, 0, 0);
        acc[mi][ni] = __builtin_amdgcn_mfma_f32_16x16x32_bf16(al[mi], wr[ni], acc[mi][ni], 0, 0, 0);
      }
    __syncthreads();
  }
  // epilogue: D col = nl, row = kq*4 + r within tile
  #pragma unroll
  for (int mi=0;mi<4;mi++){
    #pragma unroll
    for (int ni=0;ni<4;ni++){
      int col = n0 + (wn16+ni)*16 + nl;
      float bv = bias ? bias[col] : 0.0f;
      #pragma unroll
      for (int r2=0;r2<4;r2++){
        int rrow = m0 + (wm16+mi)*16 + kq*4 + r2;
        if (rrow >= M) continue;
        float val = acc[mi][ni][r2] + bv;
        if (EP==1) val = msrc[(size_t)rrow*N + col] * sigm(val);
        C[(size_t)rrow*N + col] = val;
      }
    }
  }
}

// one block per (p,b): scores over q (tanh attention), softmax over q, ct, concat write
__global__ __launch_bounds__(256) void attn_k(const float* __restrict__ Qh, const float* __restrict__ Ph,
   const float* __restrict__ qrep, const float* __restrict__ prep, const float* __restrict__ v,
   const float* __restrict__ qmask, float* __restrict__ xcat)
{
  int p = blockIdx.x, b = blockIdx.y;
  int tid = threadIdx.x;
  __shared__ float ph[HH];
  __shared__ float vv[HH];
  __shared__ float sc[64];
  size_t pb = (size_t)p*BB + b;
  ph[tid] = Ph[pb*HH + tid];
  vv[tid] = v[tid];
  xcat[pb*512 + tid] = prep[pb*II + tid];
  __syncthreads();
  int wid = tid >> 6, lane = tid & 63;
  for (int q = wid; q < TPQ; q += 4){
    const float* qh = Qh + ((size_t)q*BB + b)*HH;
    float s = 0.0f;
    for (int hh = lane; hh < HH; hh += 64)
      s += vv[hh]*tanhfast(qh[hh] + ph[hh]);
    #pragma unroll
    for (int off=32; off>0; off>>=1) s += __shfl_xor(s, off);
    if (lane==0) sc[q] = s;
  }
  __syncthreads();
  if (wid==0){
    float m = (lane < TPQ) ? qmask[lane*BB + b] : 0.0f;
    float val = (lane < TPQ) ? (m*sc[lane] + (1.0f-m)*(-1e30f)) : -INFINITY;
    float mx = val;
    #pragma unroll
    for (int off=32; off>0; off>>=1) mx = fmaxf(mx, __shfl_xor(mx, off));
    float e = (lane < TPQ) ? __expf(val - mx) : 0.0f;
    float sum = e;
    #pragma unroll
    for (int off=32; off>0; off>>=1) sum += __shfl_xor(sum, off);
    if (lane < TPQ) sc[lane] = e / sum;
  }
  __syncthreads();
  float acc = 0.0f;
  for (int q=0;q<TPQ;q++)
    acc += sc[q] * qrep[((size_t)q*BB + b)*II + tid];
  xcat[pb*512 + 256 + tid] = acc;
}

// ---------------------------------------------------------------------------
// Persistent MFMA GRU scan (R5 body, measured 645us/layer).
// grid = 32 (b,dir), block = 512. Full Whh (bf16) in regs. h: 256-bf16
// ping-pong LDS broadcast. xv loaded at top of SAME step (the vmcnt wait must
// land BEFORE the epilogue's global stores -- loads/stores share vmcnt).
// ---------------------------------------------------------------------------
__global__ __launch_bounds__(512) void gru_scan_mfma(
    const float* __restrict__ xg,    // [TPP][16][1536]
    const float* __restrict__ Whh,   // [2][768][256]
    const float* __restrict__ bhh,   // [2][768]
    float* __restrict__ out)         // [TPP][16][512]
{
  __shared__ u16 hbuf[2][256];

  const int b   = blockIdx.x & 15;
  const int dir = blockIdx.x >> 4;
  const int tid  = threadIdx.x;
  const int wv   = tid >> 6;
  const int lane = tid & 63;
  const int nl   = lane & 15;
  const int kq   = lane >> 4;

  ((u16*)hbuf)[tid] = 0;

  // Whh fragments bf16, all in registers. 16x16x32 B layout: n=lane&15, k=ks*32+kq*8+e
  bf16x8 wreg[8][6];
  #pragma unroll
  for (int ks=0; ks<8; ks++){
    #pragma unroll
    for (int gg=0; gg<2; gg++){
      #pragma unroll
      for (int gi=0; gi<3; gi++){
        int nrow = gi*256 + wv*32 + gg*16 + nl;
        const float* wsrc = Whh + (size_t)dir*768*256 + (size_t)nrow*256 + ks*32 + kq*8;
        float4 lo = *reinterpret_cast<const float4*>(wsrc);
        float4 hi = *reinterpret_cast<const float4*>(wsrc+4);
        bf16x8 f;
        f[0]=f2bf(lo.x); f[1]=f2bf(lo.y); f[2]=f2bf(lo.z); f[3]=f2bf(lo.w);
        f[4]=f2bf(hi.x); f[5]=f2bf(hi.y); f[6]=f2bf(hi.z); f[7]=f2bf(hi.w);
        wreg[ks][gg*3+gi] = f;
      }
    }
  }

  float bias[2][3];
  #pragma unroll
  for (int gg=0; gg<2; gg++)
    #pragma unroll
    for (int gi=0; gi<3; gi++)
      bias[gg][gi] = bhh[dir*768 + gi*256 + wv*32 + gg*16 + nl];

  // lane's xg column base: dir*768 + gi*256 + (wv*32 + gg*16 + nl)
  const float* xb = xg + dir*768 + wv*32 + nl;

  float hold[2] = {0.0f, 0.0f};

  __syncthreads();

  #pragma unroll 1
  for (int s=0; s<TPP; s++){
    const int t = dir ? (TPP-1-s) : s;

    // xg values for this step (consumed in epilogue; latency hides under MFMA)
    float xv[2][3];
    {
      size_t ro = (size_t)(t*16 + b)*1536;
      #pragma unroll
      for (int gg=0; gg<2; gg++)
        #pragma unroll
        for (int gi=0; gi<3; gi++)
          xv[gg][gi] = xb[ro + gi*256 + gg*16];
    }

    f32x4 acc[2][3];
    #pragma unroll
    for (int gg=0; gg<2; gg++)
      #pragma unroll
      for (int gi=0; gi<3; gi++)
        acc[gg][gi] = (f32x4){0.f,0.f,0.f,0.f};

    // A frags: broadcast h (bf16). byte addr = ks*64 + kq*16, independent of nl.
    const char* hp = (const char*)hbuf[s&1];
    bf16x8 a = *reinterpret_cast<const bf16x8*>(hp + kq*16);
    #pragma unroll
    for (int ks=0; ks<8; ks++){
      bf16x8 an;
      if (ks < 7)
        an = *reinterpret_cast<const bf16x8*>(hp + (ks+1)*64 + kq*16);
      #pragma unroll
      for (int gg=0; gg<2; gg++)
        #pragma unroll
        for (int gi=0; gi<3; gi++)
          acc[gg][gi] = __builtin_amdgcn_mfma_f32_16x16x32_bf16(a, wreg[ks][gg*3+gi], acc[gg][gi], 0, 0, 0);
      if (ks < 7) a = an;
    }

    // epilogue: D row 0 lives in lanes 0..15, reg 0
    if (lane < 16){
      u16* wb = hbuf[(s&1)^1];
      #pragma unroll
      for (int gg=0; gg<2; gg++){
        int j = wv*32 + gg*16 + nl;
        float r = sigm(xv[gg][0] + acc[gg][0][0] + bias[gg][0]);
        float z = sigm(xv[gg][1] + acc[gg][1][0] + bias[gg][1]);
        float n = tanhfast(xv[gg][2] + r*(acc[gg][2][0] + bias[gg][2]));
        float hv = (1.0f - z)*n + z*hold[gg];
        hold[gg] = hv;
        wb[j] = (u16)f2bf(hv);
        out[(size_t)(t*16 + b)*512 + dir*256 + j] = hv;
      }
    }
    __syncthreads();   // new h visible before next step's A reads
  }
}

extern "C" void kernel_launch(void* const* d_in, const int* in_sizes, int n_in,
                              void* d_out, int out_size, void* d_ws, size_t ws_size,
                              hipStream_t stream)
{
  const float* prep  = (const float*)d_in[0];
  const float* qrep  = (const float*)d_in[1];
  const float* qmask = (const float*)d_in[3];
  const float* WuQ   = (const float*)d_in[4];
  const float* WuP   = (const float*)d_in[5];
  const float* v     = (const float*)d_in[6];
  const float* Wg    = (const float*)d_in[7];
  const float* Wih   = (const float*)d_in[8];
  const float* Whh   = (const float*)d_in[9];
  const float* bih   = (const float*)d_in[10];
  const float* bhh   = (const float*)d_in[11];
  float* out = (float*)d_out;

  float* ws = (float*)d_ws;
  size_t off = 0;
  float* WuQT = ws + off; off += 256*256;
  float* WuPT = ws + off; off += 256*256;
  float* Qh   = ws + off; off += (size_t)TPQ*BB*HH;
  float* Ph   = ws + off; off += (size_t)TPP*BB*HH;
  float* xcat = ws + off; off += (size_t)TPP*BB*512;
  float* ybuf = ws + off; off += (size_t)TPP*BB*512;
  float* xg   = ws + off; off += (size_t)TPP*BB*1536;
  u16*  Wb    = (u16*)(ws + off); off += (size_t)3*1536*512/2;
  u16*  Wgb   = (u16*)(ws + off); off += (size_t)512*512/2;

  auto T = [&](float* dst, const float* src, int R, int C, int st, int o){
    int n = R*C;
    transpose_k<<<dim3((n+255)/256), dim3(256), 0, stream>>>(dst, src, R, C, st, o);
  };
  T(WuQT, WuQ, 256,256,256,0);
  T(WuPT, WuP, 256,256,256,0);
  {
    int n = 3*1536*512;
    f2bf_k<<<dim3((n+255)/256), dim3(256), 0, stream>>>(Wih, Wb, n);
    n = 512*512;
    f2bf_k<<<dim3((n+255)/256), dim3(256), 0, stream>>>(Wg, Wgb, n);
  }

  // Qh = question @ WuQ.T : M=960, N=256, K=256
  gemm_f32<0><<<dim3(2, 8), dim3(256), 0, stream>>>(qrep, WuQT, nullptr, nullptr, Qh, TPQ*BB, 256, 256);
  // Ph = passage @ WuP.T : M=6400
  gemm_f32<0><<<dim3(2, 50), dim3(256), 0, stream>>>(prep, WuPT, nullptr, nullptr, Ph, TPP*BB, 256, 256);
  // attention + concat
  attn_k<<<dim3(TPP, BB), dim3(256), 0, stream>>>(Qh, Ph, qrep, prep, v, qmask, xcat);
  // gate: ybuf = xcat * sigmoid(xcat @ Wg.T)  via bf16 MFMA
  gemm_bf16_hl<1><<<dim3(4, 50), dim3(256), 0, stream>>>(xcat, Wgb, nullptr, xcat, ybuf, TPP*BB, 512, 512);

  float* cur = ybuf;
  float* nxt = xcat;
  for (int l=0;l<3;l++){
    // xg = cur @ Wih[l].T + bih[l]  via bf16 MFMA (A hi/lo split in staging)
    gemm_bf16_hl<0><<<dim3(12, 50), dim3(256), 0, stream>>>(cur, Wb + (size_t)l*1536*512,
                                                            bih + (size_t)l*1536, nullptr, xg, TPP*BB, 1536, 512);
    float* o = (l==2) ? out : nxt;
    gru_scan_mfma<<<dim3(32), dim3(512), 0, stream>>>(xg, Whh + (size_t)l*2*768*256,
                                                      bhh + (size_t)l*2*768, o);
    float* tmp = cur; cur = o; nxt = tmp;
  }
}